// Round 14
// baseline (721.472 us; speedup 1.0000x reference)
//
#include <hip/hip_runtime.h>
#include <math.h>

#define NP 512
#define TT 12
#define NB 64    // persistent blocks; each owns 8 pedestrians

typedef float f32x4 __attribute__((ext_vector_type(4)));
typedef __bf16 bf16x8 __attribute__((ext_vector_type(8)));

// ws float offsets (float units)
#define OFF_QB     0        // bf16 [2][512][64]  (32768 floats) cross-block via LLC atomics
#define OFF_XCZ    32768    // f32 [512][128]     (65536)
#define OFF_WGT    98304    // bf16 [256 g][192 k] (24576)  gates W^T rows
#define OFF_WCTXT  122880   // bf16 [128 k][64 d]  (4096)   W_in[98:162]^T
#define OFF_W1T    126976   // bf16 [2][64 m][64 k] (4096)  W1[32:160]^T halves
#define OFF_WIN01  131072   // f32 [2][128]        (256)
#define OFF_WC     131328   // f32 [2][64]         (128)
#define OFF_BASE   131456   // f32 [64]            (64)
#define OFF_W2F    131520   // bf16 [64 lane][64]  (2048)
#define OFF_BAR    133568   // int [16]            (16)

#define AT_LD64(p)   __hip_atomic_load((p), __ATOMIC_RELAXED, __HIP_MEMORY_SCOPE_AGENT)
#define AT_ST32(p,v) __hip_atomic_store((p), (v), __ATOMIC_RELAXED, __HIP_MEMORY_SCOPE_AGENT)

union BU { __bf16 h; unsigned short u; };

__global__ __launch_bounds__(256) void init_k(
    const float* __restrict__ cc, const float* __restrict__ zz,
    const float* __restrict__ W_in, const float* __restrict__ W_ih,
    const float* __restrict__ W_hh, const float* __restrict__ W_sp,
    const float* __restrict__ b_sp, const float* __restrict__ W1,
    const float* __restrict__ b1, const float* __restrict__ W2,
    float* __restrict__ ws) {
  if (blockIdx.x < 128) {
    int id = blockIdx.x * 256 + threadIdx.x;   // 0..32767
    __bf16* wgt = (__bf16*)(ws + OFF_WGT);
    for (int e = id; e < 49152; e += 32768) {
      int g = e / 192, k = e - g * 192;
      wgt[e] = (__bf16)((k < 128) ? W_ih[g * 128 + k] : W_hh[g * 64 + (k - 128)]);
    }
    if (id < 8192) {   // WCTXT[k][d] = W_in[98+d][k]
      int k = id >> 6, d = id & 63;
      ((__bf16*)(ws + OFF_WCTXT))[id] = (__bf16)W_in[(98 + d) * 128 + k];
    }
    if (id < 8192) {   // W1T[which][m][k] = W1[32+which*64+k][m]
      int which = id >> 12, m = (id >> 6) & 63, k = id & 63;
      ((__bf16*)(ws + OFF_W1T))[id] = (__bf16)W1[(32 + which * 64 + k) * 64 + m];
    }
    if (id < 256) ws[OFF_WIN01 + id] = W_in[(id >> 7) * 128 + (id & 127)];
    if (id < 128) {
      int d = id >> 6, m = id & 63;
      float s = 0.f;
      for (int e = 0; e < 32; ++e) s = fmaf(W_sp[d * 32 + e], W1[e * 64 + m], s);
      ws[OFF_WC + id] = s;
    }
    if (id < 64) {
      float s = b1[id];
      for (int e = 0; e < 32; ++e) s = fmaf(b_sp[e], W1[e * 64 + id], s);
      ws[OFF_BASE + id] = s;
    }
    if (id < 4096) {   // W2 fragment table
      int e = id & 7, f = (id >> 3) & 7, cq = id >> 6;
      int col = cq >> 2, quad = cq & 3, mt = f >> 1, kh = f & 1;
      ((__bf16*)(ws + OFF_W2F))[id] =
          (__bf16)W2[(kh * 32 + quad * 8 + e) * 64 + (mt * 16 + col)];
    }
    if (id < 16) ((int*)(ws + OFF_BAR))[id] = 0;
  } else {
    int b = blockIdx.x - 128;
    int k = threadIdx.x;
    if (k < 128) {
      float s = 0.f;
      for (int d = 0; d < 64; ++d) s = fmaf(cc[b * 64 + d], W_in[(2 + d) * 128 + k], s);
      for (int d = 0; d < 32; ++d) s = fmaf(zz[b * 32 + d], W_in[(66 + d) * 128 + k], s);
      ws[OFF_XCZ + b * 128 + k] = s;
    }
  }
}

// Persistent: 64 blocks x 256 threads, each block owns 8 pedestrians for all
// 12 steps. State (h,cs,ctx,prev,pos,P) lives in LDS. Only Q (bf16, 64KB/step)
// crosses blocks, via relaxed agent-scope atomics at the LLC. Grid barrier:
// per-step counter, relaxed atomics, NO fences (syncthreads' vmcnt drain
// orders Q stores before the increment; atomics bypass the non-coherent L2).
// Weights are read-only normal loads -> stay hot in per-XCD L2 all 12 steps.
__global__ __launch_bounds__(256) void persist_k(
    const float* __restrict__ lastpos, const int* __restrict__ nei,
    const float* __restrict__ h0, const float* __restrict__ c0,
    const float* __restrict__ obs, const float* __restrict__ epsin,
    const float* __restrict__ b_in,
    const float* __restrict__ b_ih, const float* __restrict__ b_hh,
    const float* __restrict__ Wl2p, const float* __restrict__ bl2p,
    const float* __restrict__ b2,
    float* __restrict__ out, float* __restrict__ ws) {
  __shared__ __align__(16) __bf16 Qc[2][64 * 72];      // chunk double buffer
  __shared__ __align__(16) float P8[8][64];
  __shared__ __align__(16) float h8[8][64], cs8[8][64], ctx8[8][64];
  __shared__ float prev8[8][2], pxy8[8][2];
  __shared__ __align__(16) float xv2[2][128];
  __shared__ float gl2[2][256];
  __shared__ float basev[64], wcl[128];

  int t = threadIdx.x;
  int b = blockIdx.x;
  int lane = t & 63, w = t >> 6;
  int quad = lane >> 4, col = lane & 15;
  int* bar = (int*)(ws + OFF_BAR);
  const __bf16* wgt   = (const __bf16*)(ws + OFF_WGT);
  const __bf16* wctxT = (const __bf16*)(ws + OFF_WCTXT);
  const __bf16* w1T   = (const __bf16*)(ws + OFF_W1T);

  // ---- one-time init ----
  for (int e = t; e < 512; e += 256) {
    int pp = e >> 6, u = e & 63;
    h8[pp][u]  = h0[(b * 8 + pp) * 64 + u];
    cs8[pp][u] = c0[(b * 8 + pp) * 64 + u];
    ctx8[pp][u] = 0.f;
  }
  if (t < 16) {
    int pp = t >> 1, d = t & 1;
    prev8[pp][d] = lastpos[(b * 8 + pp) * 2 + d];
    pxy8[pp][d]  = obs[7 * 1024 + (b * 8 + pp) * 2 + d];
  }
  if (t < 64) basev[t] = ws[OFF_BASE + t];
  else if (t < 192) wcl[t - 64] = ws[OFF_WC + (t - 64)];
  // W2 MFMA fragments (held all kernel)
  const __bf16* wf = (const __bf16*)(ws + OFF_W2F) + (col * 4 + quad) * 64;
  bf16x8 bf00 = *(const bf16x8*)&wf[0];
  bf16x8 bf01 = *(const bf16x8*)&wf[8];
  bf16x8 bf10 = *(const bf16x8*)&wf[16];
  bf16x8 bf11 = *(const bf16x8*)&wf[24];
  bf16x8 bf20 = *(const bf16x8*)&wf[32];
  bf16x8 bf21 = *(const bf16x8*)&wf[40];
  bf16x8 bf30 = *(const bf16x8*)&wf[48];
  bf16x8 bf31 = *(const bf16x8*)&wf[56];
  __syncthreads();

  for (int st = 0; st < TT; ++st) {
    // ================= row phase: 2 peds per iteration =================
    for (int pp2 = 0; pp2 < 4; ++pp2) {
      int pa = pp2 * 2;
      {   // x: t covers (pe, k)
        int pe = t >> 7, k = t & 127, lp = pa + pe, gp = b * 8 + lp;
        float a0 = ws[OFF_XCZ + gp * 128 + k] + b_in[k] +
                   prev8[lp][0] * ws[OFF_WIN01 + k] +
                   prev8[lp][1] * ws[OFF_WIN01 + 128 + k];
        const __bf16* wk = wctxT + k * 64;
        float s0 = 0.f, s1 = 0.f;
        #pragma unroll
        for (int d = 0; d < 64; d += 8) {
          bf16x8 wv = *(const bf16x8*)&wk[d];
          f32x4 c0 = *(const f32x4*)&ctx8[lp][d];
          f32x4 c1 = *(const f32x4*)&ctx8[lp][d + 4];
          s0 = fmaf(c0[0], (float)wv[0], s0); s1 = fmaf(c0[1], (float)wv[1], s1);
          s0 = fmaf(c0[2], (float)wv[2], s0); s1 = fmaf(c0[3], (float)wv[3], s1);
          s0 = fmaf(c1[0], (float)wv[4], s0); s1 = fmaf(c1[1], (float)wv[5], s1);
          s0 = fmaf(c1[2], (float)wv[6], s0); s1 = fmaf(c1[3], (float)wv[7], s1);
        }
        xv2[pe][k] = fmaxf(a0 + s0 + s1, 0.f);
      }
      __syncthreads();
      {   // gates for both peds, weight row loaded once
        int g = t;
        const __bf16* wg = wgt + g * 192;
        float biasg = b_ih[g] + b_hh[g];
        float A0 = 0.f, A1 = 0.f, B0 = 0.f, B1 = 0.f;
        #pragma unroll
        for (int kk = 0; kk < 128; kk += 8) {
          bf16x8 wv = *(const bf16x8*)&wg[kk];
          f32x4 xa0 = *(const f32x4*)&xv2[0][kk];
          f32x4 xa1 = *(const f32x4*)&xv2[0][kk + 4];
          f32x4 xb0 = *(const f32x4*)&xv2[1][kk];
          f32x4 xb1 = *(const f32x4*)&xv2[1][kk + 4];
          #pragma unroll
          for (int e = 0; e < 4; ++e) {
            float wa = (float)wv[e], wb2 = (float)wv[e + 4];
            A0 = fmaf(xa0[e], wa, A0); A1 = fmaf(xa1[e], wb2, A1);
            B0 = fmaf(xb0[e], wa, B0); B1 = fmaf(xb1[e], wb2, B1);
          }
        }
        #pragma unroll
        for (int kk = 0; kk < 64; kk += 8) {
          bf16x8 wv = *(const bf16x8*)&wg[128 + kk];
          f32x4 ha0 = *(const f32x4*)&h8[pa][kk];
          f32x4 ha1 = *(const f32x4*)&h8[pa][kk + 4];
          f32x4 hb0 = *(const f32x4*)&h8[pa + 1][kk];
          f32x4 hb1 = *(const f32x4*)&h8[pa + 1][kk + 4];
          #pragma unroll
          for (int e = 0; e < 4; ++e) {
            float wa = (float)wv[e], wb2 = (float)wv[e + 4];
            A0 = fmaf(ha0[e], wa, A0); A1 = fmaf(ha1[e], wb2, A1);
            B0 = fmaf(hb0[e], wa, B0); B1 = fmaf(hb1[e], wb2, B1);
          }
        }
        gl2[0][g] = biasg + A0 + A1;
        gl2[1][g] = biasg + B0 + B1;
      }
      __syncthreads();
      if (t < 128) {   // LSTM for both peds
        int pe = t >> 6, u = t & 63, lp = pa + pe;
        float ig = gl2[pe][u], fg = gl2[pe][64 + u];
        float gg = gl2[pe][128 + u], og = gl2[pe][192 + u];
        float is = 1.f / (1.f + expf(-ig));
        float fs = 1.f / (1.f + expf(-fg));
        float os = 1.f / (1.f + expf(-og));
        float cn = fs * cs8[lp][u] + is * tanhf(gg);
        cs8[lp][u] = cn;
        h8[lp][u] = os * tanhf(cn);
      }
      __syncthreads();
      {   // Q (atomic->LLC) and P (LDS) for both peds
        int pe = t >> 7, which = (t >> 6) & 1, m = t & 63;
        int lp = pa + pe, gp = b * 8 + lp;
        const __bf16* wr = w1T + which * 4096 + m * 64;
        float s0 = 0.f, s1 = 0.f;
        #pragma unroll
        for (int k = 0; k < 64; k += 8) {
          bf16x8 wv = *(const bf16x8*)&wr[k];
          f32x4 hv0 = *(const f32x4*)&h8[lp][k];
          f32x4 hv1 = *(const f32x4*)&h8[lp][k + 4];
          s0 = fmaf(hv0[0], (float)wv[0], s0); s1 = fmaf(hv0[1], (float)wv[1], s1);
          s0 = fmaf(hv0[2], (float)wv[2], s0); s1 = fmaf(hv0[3], (float)wv[3], s1);
          s0 = fmaf(hv1[0], (float)wv[4], s0); s1 = fmaf(hv1[1], (float)wv[5], s1);
          s0 = fmaf(hv1[2], (float)wv[6], s0); s1 = fmaf(hv1[3], (float)wv[7], s1);
        }
        float sv = s0 + s1;
        float px = pxy8[lp][0], py = pxy8[lp][1];
        if (which == 0) {
          float qv = sv + basev[m] - px * wcl[m] - py * wcl[64 + m];
          float qlo = __shfl(qv, (lane << 1));
          float qhi = __shfl(qv, (lane << 1) + 1);
          if (lane < 32) {
            BU ulo, uhi; ulo.h = (__bf16)qlo; uhi.h = (__bf16)qhi;
            unsigned int u32 = ((unsigned int)uhi.u << 16) | ulo.u;
            unsigned int* qdst =
                (unsigned int*)((__bf16*)(ws + OFF_QB) + (st & 1) * 32768);
            AT_ST32(qdst + gp * 32 + lane, u32);
          }
        } else {
          P8[lp][m] = sv + px * wcl[m] + py * wcl[64 + m];
        }
      }
    }

    // ================= grid barrier (no fences) =================
    __syncthreads();      // drains every wave's Q stores (vmcnt) before barrier
    if (t == 0) {
      __hip_atomic_fetch_add(&bar[st], 1, __ATOMIC_RELAXED, __HIP_MEMORY_SCOPE_AGENT);
      while (__hip_atomic_load(&bar[st], __ATOMIC_RELAXED, __HIP_MEMORY_SCOPE_AGENT) < NB)
        __builtin_amdgcn_s_sleep(2);
    }
    __syncthreads();

    // ================= pool phase =================
    const unsigned long long* qsrc =
        (const unsigned long long*)((__bf16*)(ws + OFF_QB) + (st & 1) * 32768);
    int lpA = w * 2, lpB = w * 2 + 1;
    int gpA = b * 8 + lpA, gpB = b * 8 + lpB;
    const int* neiA = nei + ((size_t)st * NP + gpA) * NP;
    const int* neiB = nei + ((size_t)st * NP + gpB) * NP;
    float vmA0 = -1e30f, vmA1 = -1e30f, vmA2 = -1e30f, vmA3 = -1e30f;
    float vmB0 = -1e30f, vmB1 = -1e30f, vmB2 = -1e30f, vmB3 = -1e30f;

    unsigned long long v0, v1, v2, v3;
    v0 = AT_LD64(qsrc + 0 * 256 + t); v1 = AT_LD64(qsrc + 1 * 256 + t);
    v2 = AT_LD64(qsrc + 2 * 256 + t); v3 = AT_LD64(qsrc + 3 * 256 + t);
    {
      int f0 = t, f1 = 256 + t, f2 = 512 + t, f3 = 768 + t;
      *(unsigned long long*)&Qc[0][(f0 >> 4) * 72 + (f0 & 15) * 4] = v0;
      *(unsigned long long*)&Qc[0][(f1 >> 4) * 72 + (f1 & 15) * 4] = v1;
      *(unsigned long long*)&Qc[0][(f2 >> 4) * 72 + (f2 & 15) * 4] = v2;
      *(unsigned long long*)&Qc[0][(f3 >> 4) * 72 + (f3 & 15) * 4] = v3;
    }
    __syncthreads();

    for (int c = 0; c < 8; ++c) {
      int buf = c & 1;
      if (c < 7) {
        v0 = AT_LD64(qsrc + (c + 1) * 1024 + 0 * 256 + t);
        v1 = AT_LD64(qsrc + (c + 1) * 1024 + 1 * 256 + t);
        v2 = AT_LD64(qsrc + (c + 1) * 1024 + 2 * 256 + t);
        v3 = AT_LD64(qsrc + (c + 1) * 1024 + 3 * 256 + t);
      }
      int mvA = neiA[c * 64 + lane];
      int mvB = neiB[c * 64 + lane];
      #pragma unroll
      for (int ped = 0; ped < 2; ++ped) {
        int lp = ped ? lpB : lpA;
        int mv = ped ? mvB : mvA;
        f32x4 pa0 = *(const f32x4*)&P8[lp][quad * 8];
        f32x4 pa1 = *(const f32x4*)&P8[lp][quad * 8 + 4];
        f32x4 pb0 = *(const f32x4*)&P8[lp][32 + quad * 8];
        f32x4 pb1 = *(const f32x4*)&P8[lp][32 + quad * 8 + 4];
        #pragma unroll
        for (int jt = 0; jt < 4; ++jt) {
          int jrow = jt * 16 + col;
          bf16x8 q0 = *(const bf16x8*)&Qc[buf][jrow * 72 + quad * 8];
          bf16x8 q1 = *(const bf16x8*)&Qc[buf][jrow * 72 + 32 + quad * 8];
          bf16x8 a0, a1;
          #pragma unroll
          for (int e = 0; e < 4; ++e) {
            a0[e]     = (__bf16)fmaxf((float)q0[e]     + pa0[e], 0.f);
            a0[e + 4] = (__bf16)fmaxf((float)q0[e + 4] + pa1[e], 0.f);
            a1[e]     = (__bf16)fmaxf((float)q1[e]     + pb0[e], 0.f);
            a1[e + 4] = (__bf16)fmaxf((float)q1[e + 4] + pb1[e], 0.f);
          }
          int mrow = jt * 16 + quad * 4;
          bool mk0 = __shfl(mv, mrow)     > 0;
          bool mk1 = __shfl(mv, mrow + 1) > 0;
          bool mk2 = __shfl(mv, mrow + 2) > 0;
          bool mk3 = __shfl(mv, mrow + 3) > 0;
          f32x4 acc;
          float* vm0p = ped ? &vmB0 : &vmA0;
          float* vm1p = ped ? &vmB1 : &vmA1;
          float* vm2p = ped ? &vmB2 : &vmA2;
          float* vm3p = ped ? &vmB3 : &vmA3;
          acc = (f32x4){0.f, 0.f, 0.f, 0.f};
          acc = __builtin_amdgcn_mfma_f32_16x16x32_bf16(a0, bf00, acc, 0, 0, 0);
          acc = __builtin_amdgcn_mfma_f32_16x16x32_bf16(a1, bf01, acc, 0, 0, 0);
          *vm0p = fmaxf(*vm0p, mk0 ? acc[0] : -1e30f);
          *vm0p = fmaxf(*vm0p, mk1 ? acc[1] : -1e30f);
          *vm0p = fmaxf(*vm0p, mk2 ? acc[2] : -1e30f);
          *vm0p = fmaxf(*vm0p, mk3 ? acc[3] : -1e30f);
          acc = (f32x4){0.f, 0.f, 0.f, 0.f};
          acc = __builtin_amdgcn_mfma_f32_16x16x32_bf16(a0, bf10, acc, 0, 0, 0);
          acc = __builtin_amdgcn_mfma_f32_16x16x32_bf16(a1, bf11, acc, 0, 0, 0);
          *vm1p = fmaxf(*vm1p, mk0 ? acc[0] : -1e30f);
          *vm1p = fmaxf(*vm1p, mk1 ? acc[1] : -1e30f);
          *vm1p = fmaxf(*vm1p, mk2 ? acc[2] : -1e30f);
          *vm1p = fmaxf(*vm1p, mk3 ? acc[3] : -1e30f);
          acc = (f32x4){0.f, 0.f, 0.f, 0.f};
          acc = __builtin_amdgcn_mfma_f32_16x16x32_bf16(a0, bf20, acc, 0, 0, 0);
          acc = __builtin_amdgcn_mfma_f32_16x16x32_bf16(a1, bf21, acc, 0, 0, 0);
          *vm2p = fmaxf(*vm2p, mk0 ? acc[0] : -1e30f);
          *vm2p = fmaxf(*vm2p, mk1 ? acc[1] : -1e30f);
          *vm2p = fmaxf(*vm2p, mk2 ? acc[2] : -1e30f);
          *vm2p = fmaxf(*vm2p, mk3 ? acc[3] : -1e30f);
          acc = (f32x4){0.f, 0.f, 0.f, 0.f};
          acc = __builtin_amdgcn_mfma_f32_16x16x32_bf16(a0, bf30, acc, 0, 0, 0);
          acc = __builtin_amdgcn_mfma_f32_16x16x32_bf16(a1, bf31, acc, 0, 0, 0);
          *vm3p = fmaxf(*vm3p, mk0 ? acc[0] : -1e30f);
          *vm3p = fmaxf(*vm3p, mk1 ? acc[1] : -1e30f);
          *vm3p = fmaxf(*vm3p, mk2 ? acc[2] : -1e30f);
          *vm3p = fmaxf(*vm3p, mk3 ? acc[3] : -1e30f);
        }
      }
      if (c < 7) {
        int nb = buf ^ 1;
        int f0 = t, f1 = 256 + t, f2 = 512 + t, f3 = 768 + t;
        *(unsigned long long*)&Qc[nb][(f0 >> 4) * 72 + (f0 & 15) * 4] = v0;
        *(unsigned long long*)&Qc[nb][(f1 >> 4) * 72 + (f1 & 15) * 4] = v1;
        *(unsigned long long*)&Qc[nb][(f2 >> 4) * 72 + (f2 & 15) * 4] = v2;
        *(unsigned long long*)&Qc[nb][(f3 >> 4) * 72 + (f3 & 15) * 4] = v3;
      }
      __syncthreads();
    }

    // per-ped reduce + epilogue (wave-autonomous)
    #pragma unroll
    for (int ped = 0; ped < 2; ++ped) {
      int lp = ped ? lpB : lpA, gp = ped ? gpB : gpA;
      float m0v = ped ? vmB0 : vmA0, m1v = ped ? vmB1 : vmA1;
      float m2v = ped ? vmB2 : vmA2, m3v = ped ? vmB3 : vmA3;
      m0v = fmaxf(m0v, __shfl_xor(m0v, 16)); m0v = fmaxf(m0v, __shfl_xor(m0v, 32));
      m1v = fmaxf(m1v, __shfl_xor(m1v, 16)); m1v = fmaxf(m1v, __shfl_xor(m1v, 32));
      m2v = fmaxf(m2v, __shfl_xor(m2v, 16)); m2v = fmaxf(m2v, __shfl_xor(m2v, 32));
      m3v = fmaxf(m3v, __shfl_xor(m3v, 16)); m3v = fmaxf(m3v, __shfl_xor(m3v, 32));
      int mt = lane >> 4;
      float cval = (mt == 0) ? m0v : (mt == 1) ? m1v : (mt == 2) ? m2v : m3v;
      cval = fmaxf(cval + b2[lane], 0.f);
      ctx8[lp][lane] = cval;
      // epilogue
      int l = lane;
      float sc0 = cval * Wl2p[(32 + l) * 2 + 0];
      float sc1 = cval * Wl2p[(32 + l) * 2 + 1];
      float e0s = 0.f, e1s = 0.f, f0s = 0.f, f1s = 0.f;
      if (l < 32) {
        float hm = h8[lp][l];
        e0s = hm * Wl2p[l * 2 + 0]; e1s = hm * Wl2p[l * 2 + 1];
        float hv = h8[lp][32 + l];
        f0s = hv * Wl2p[l * 2 + 0]; f1s = hv * Wl2p[l * 2 + 1];
      }
      for (int off = 32; off >= 1; off >>= 1) {
        sc0 += __shfl_down(sc0, off);
        sc1 += __shfl_down(sc1, off);
        e0s += __shfl_down(e0s, off);
        e1s += __shfl_down(e1s, off);
        f0s += __shfl_down(f0s, off);
        f1s += __shfl_down(f1s, off);
      }
      if (l == 0) {
        float mu0 = e0s + sc0 + bl2p[0], mu1 = e1s + sc1 + bl2p[1];
        float lv0 = f0s + sc0 + bl2p[0], lv1 = f1s + sc1 + bl2p[1];
        float ee0 = epsin[st * 1024 + gp * 2 + 0];
        float ee1 = epsin[st * 1024 + gp * 2 + 1];
        float p0 = mu0 + ee0 * expf(0.5f * lv0);
        float p1 = mu1 + ee1 * expf(0.5f * lv1);
        out[st * 1024 + gp * 2 + 0] = p0;
        out[st * 1024 + gp * 2 + 1] = p1;
        out[12288 + st * 1024 + gp * 2 + 0] = mu0;
        out[12288 + st * 1024 + gp * 2 + 1] = mu1;
        out[24576 + st * 1024 + gp * 2 + 0] = lv0;
        out[24576 + st * 1024 + gp * 2 + 1] = lv1;
        prev8[lp][0] = p0; prev8[lp][1] = p1;
        pxy8[lp][0] += p0; pxy8[lp][1] += p1;
      }
    }
    __syncthreads();   // ctx8/prev8/pxy8 visible to all waves for next row
  }
}

extern "C" void kernel_launch(void* const* d_in, const int* in_sizes, int n_in,
                              void* d_out, int out_size, void* d_ws, size_t ws_size,
                              hipStream_t stream) {
  const float* lastpos = (const float*)d_in[0];
  const float* cc      = (const float*)d_in[1];
  const float* zz      = (const float*)d_in[2];
  const float* obs     = (const float*)d_in[3];
  const int*   nei     = (const int*)d_in[4];
  const float* h0      = (const float*)d_in[6];
  const float* c0      = (const float*)d_in[7];
  const float* eps     = (const float*)d_in[8];
  const float* W_in    = (const float*)d_in[9];
  const float* b_in    = (const float*)d_in[10];
  const float* W_ih    = (const float*)d_in[11];
  const float* W_hh    = (const float*)d_in[12];
  const float* b_ih    = (const float*)d_in[13];
  const float* b_hh    = (const float*)d_in[14];
  const float* W_l2p   = (const float*)d_in[15];
  const float* b_l2p   = (const float*)d_in[16];
  const float* W_sp    = (const float*)d_in[17];
  const float* b_sp    = (const float*)d_in[18];
  const float* W1      = (const float*)d_in[19];
  const float* b1      = (const float*)d_in[20];
  const float* W2      = (const float*)d_in[21];
  const float* b2      = (const float*)d_in[22];
  float* out = (float*)d_out;
  float* ws  = (float*)d_ws;

  hipLaunchKernelGGL(init_k, dim3(640), dim3(256), 0, stream,
                     cc, zz, W_in, W_ih, W_hh, W_sp, b_sp, W1, b1, W2, ws);
  hipLaunchKernelGGL(persist_k, dim3(NB), dim3(256), 0, stream,
                     lastpos, nei, h0, c0, obs, eps,
                     b_in, b_ih, b_hh, W_l2p, b_l2p, b2, out, ws);
}

// Round 15
// 369.008 us; speedup vs baseline: 1.9552x; 1.9552x over previous
//
#include <hip/hip_runtime.h>
#include <math.h>

#define NP 512
#define TT 12
#define NB 256   // persistent blocks; each owns 2 pedestrians (guaranteed co-resident)

typedef float f32x4 __attribute__((ext_vector_type(4)));
typedef __bf16 bf16x8 __attribute__((ext_vector_type(8)));

// ws float offsets (float units)
#define OFF_QB     0        // bf16 [2][512][64]  (32768 floats) cross-block via LLC atomics
#define OFF_XCZ    32768    // f32 [512][128]     (65536)
#define OFF_WGT    98304    // bf16 [256 g][192 k] (24576)
#define OFF_WCTXT  122880   // bf16 [128 k][64 d]  (4096)
#define OFF_W1T    126976   // bf16 [2][64 m][64 k] (4096)
#define OFF_WIN01  131072   // f32 [2][128]        (256)
#define OFF_WC     131328   // f32 [2][64]         (128)
#define OFF_BASE   131456   // f32 [64]            (64)
#define OFF_W2F    131520   // bf16 [64 lane][64]  (2048)
#define OFF_BAR    133568   // int [16]
// total ~534 KB

#define AT_LD64(p)   __hip_atomic_load((p), __ATOMIC_RELAXED, __HIP_MEMORY_SCOPE_AGENT)
#define AT_ST32(p,v) __hip_atomic_store((p), (v), __ATOMIC_RELAXED, __HIP_MEMORY_SCOPE_AGENT)

union BU { __bf16 h; unsigned short u; };

__global__ __launch_bounds__(256) void init_k(
    const float* __restrict__ cc, const float* __restrict__ zz,
    const float* __restrict__ W_in, const float* __restrict__ W_ih,
    const float* __restrict__ W_hh, const float* __restrict__ W_sp,
    const float* __restrict__ b_sp, const float* __restrict__ W1,
    const float* __restrict__ b1, const float* __restrict__ W2,
    float* __restrict__ ws) {
  if (blockIdx.x < 128) {
    int id = blockIdx.x * 256 + threadIdx.x;   // 0..32767
    __bf16* wgt = (__bf16*)(ws + OFF_WGT);
    for (int e = id; e < 49152; e += 32768) {
      int g = e / 192, k = e - g * 192;
      wgt[e] = (__bf16)((k < 128) ? W_ih[g * 128 + k] : W_hh[g * 64 + (k - 128)]);
    }
    if (id < 8192) {   // WCTXT[k][d] = W_in[98+d][k]
      int k = id >> 6, d = id & 63;
      ((__bf16*)(ws + OFF_WCTXT))[id] = (__bf16)W_in[(98 + d) * 128 + k];
    }
    if (id < 8192) {   // W1T[which][m][k] = W1[32+which*64+k][m]
      int which = id >> 12, m = (id >> 6) & 63, k = id & 63;
      ((__bf16*)(ws + OFF_W1T))[id] = (__bf16)W1[(32 + which * 64 + k) * 64 + m];
    }
    if (id < 256) ws[OFF_WIN01 + id] = W_in[(id >> 7) * 128 + (id & 127)];
    if (id < 128) {
      int d = id >> 6, m = id & 63;
      float s = 0.f;
      for (int e = 0; e < 32; ++e) s = fmaf(W_sp[d * 32 + e], W1[e * 64 + m], s);
      ws[OFF_WC + id] = s;
    }
    if (id < 64) {
      float s = b1[id];
      for (int e = 0; e < 32; ++e) s = fmaf(b_sp[e], W1[e * 64 + id], s);
      ws[OFF_BASE + id] = s;
    }
    if (id < 4096) {   // W2 fragment table
      int e = id & 7, f = (id >> 3) & 7, cq = id >> 6;
      int col = cq >> 2, quad = cq & 3, mt = f >> 1, kh = f & 1;
      ((__bf16*)(ws + OFF_W2F))[id] =
          (__bf16)W2[(kh * 32 + quad * 8 + e) * 64 + (mt * 16 + col)];
    }
    if (id < 16) ((int*)(ws + OFF_BAR))[id] = 0;
  } else {
    int b = blockIdx.x - 128;
    int k = threadIdx.x;
    if (k < 128) {
      float s = 0.f;
      for (int d = 0; d < 64; ++d) s = fmaf(cc[b * 64 + d], W_in[(2 + d) * 128 + k], s);
      for (int d = 0; d < 32; ++d) s = fmaf(zz[b * 32 + d], W_in[(66 + d) * 128 + k], s);
      ws[OFF_XCZ + b * 128 + k] = s;
    }
  }
}

// Persistent: 256 blocks x 256 threads, each block owns 2 pedestrians for all
// 12 steps. State lives in LDS. Only Q (bf16, 64KB/step) crosses blocks, via
// relaxed agent-scope atomics at the LLC (verified cheap: R14 FETCH=10MB).
// Grid barrier: per-step counter, relaxed atomics, no fences (syncthreads'
// vmcnt drain orders Q stores before the increment). Pool j-range split
// across the 4 waves; cross-wave max via LDS.
__global__ __launch_bounds__(256) void persist_k(
    const float* __restrict__ lastpos, const int* __restrict__ nei,
    const float* __restrict__ h0, const float* __restrict__ c0,
    const float* __restrict__ obs, const float* __restrict__ epsin,
    const float* __restrict__ b_in,
    const float* __restrict__ b_ih, const float* __restrict__ b_hh,
    const float* __restrict__ Wl2p, const float* __restrict__ bl2p,
    const float* __restrict__ b2,
    float* __restrict__ out, float* __restrict__ ws) {
  __shared__ __align__(16) __bf16 Qc[2][64 * 72];
  __shared__ __align__(16) float P2[2][64];
  __shared__ __align__(16) float h2[2][64], cs2[2][64], ctx2[2][64];
  __shared__ float prev2[2][2], pxy2[2][2];
  __shared__ __align__(16) float xv2[2][128];
  __shared__ float gl2[2][256];
  __shared__ float basev[64], wcl[128];
  __shared__ float red[4][2][64];

  int t = threadIdx.x;
  int b = blockIdx.x;
  int lane = t & 63, w = t >> 6;
  int quad = lane >> 4, col = lane & 15;
  int* bar = (int*)(ws + OFF_BAR);
  const __bf16* wgt   = (const __bf16*)(ws + OFF_WGT);
  const __bf16* wctxT = (const __bf16*)(ws + OFF_WCTXT);
  const __bf16* w1T   = (const __bf16*)(ws + OFF_W1T);

  // ---- one-time init ----
  if (t < 128) {
    int pp = t >> 6, u = t & 63;
    h2[pp][u]  = h0[(b * 2 + pp) * 64 + u];
    cs2[pp][u] = c0[(b * 2 + pp) * 64 + u];
    ctx2[pp][u] = 0.f;
  } else if (t < 192) {
    basev[t - 128] = ws[OFF_BASE + (t - 128)];
  }
  if (t < 4) {
    int pp = t >> 1, d = t & 1;
    prev2[pp][d] = lastpos[(b * 2 + pp) * 2 + d];
    pxy2[pp][d]  = obs[7 * 1024 + (b * 2 + pp) * 2 + d];
  }
  if (t >= 192 && t < 256) { wcl[t - 192] = ws[OFF_WC + (t - 192)]; }
  if (t >= 64 && t < 128)  { wcl[t]       = ws[OFF_WC + t]; }
  const __bf16* wf = (const __bf16*)(ws + OFF_W2F) + (col * 4 + quad) * 64;
  bf16x8 bf00 = *(const bf16x8*)&wf[0];
  bf16x8 bf01 = *(const bf16x8*)&wf[8];
  bf16x8 bf10 = *(const bf16x8*)&wf[16];
  bf16x8 bf11 = *(const bf16x8*)&wf[24];
  bf16x8 bf20 = *(const bf16x8*)&wf[32];
  bf16x8 bf21 = *(const bf16x8*)&wf[40];
  bf16x8 bf30 = *(const bf16x8*)&wf[48];
  bf16x8 bf31 = *(const bf16x8*)&wf[56];
  __syncthreads();

  for (int st = 0; st < TT; ++st) {
    // ================= row phase (2 peds in parallel) =================
    {   // x: t covers (pe, k)
      int pe = t >> 7, k = t & 127, gp = b * 2 + pe;
      float a0 = ws[OFF_XCZ + gp * 128 + k] + b_in[k] +
                 prev2[pe][0] * ws[OFF_WIN01 + k] +
                 prev2[pe][1] * ws[OFF_WIN01 + 128 + k];
      const __bf16* wk = wctxT + k * 64;
      float s0 = 0.f, s1 = 0.f;
      #pragma unroll
      for (int d = 0; d < 64; d += 8) {
        bf16x8 wv = *(const bf16x8*)&wk[d];
        f32x4 c0v = *(const f32x4*)&ctx2[pe][d];
        f32x4 c1v = *(const f32x4*)&ctx2[pe][d + 4];
        s0 = fmaf(c0v[0], (float)wv[0], s0); s1 = fmaf(c0v[1], (float)wv[1], s1);
        s0 = fmaf(c0v[2], (float)wv[2], s0); s1 = fmaf(c0v[3], (float)wv[3], s1);
        s0 = fmaf(c1v[0], (float)wv[4], s0); s1 = fmaf(c1v[1], (float)wv[5], s1);
        s0 = fmaf(c1v[2], (float)wv[6], s0); s1 = fmaf(c1v[3], (float)wv[7], s1);
      }
      xv2[pe][k] = fmaxf(a0 + s0 + s1, 0.f);
    }
    __syncthreads();
    {   // gates for both peds, weight row loaded once
      int g = t;
      const __bf16* wg = wgt + g * 192;
      float biasg = b_ih[g] + b_hh[g];
      float A0 = 0.f, A1 = 0.f, B0 = 0.f, B1 = 0.f;
      #pragma unroll
      for (int kk = 0; kk < 128; kk += 8) {
        bf16x8 wv = *(const bf16x8*)&wg[kk];
        f32x4 xa0 = *(const f32x4*)&xv2[0][kk];
        f32x4 xa1 = *(const f32x4*)&xv2[0][kk + 4];
        f32x4 xb0 = *(const f32x4*)&xv2[1][kk];
        f32x4 xb1 = *(const f32x4*)&xv2[1][kk + 4];
        #pragma unroll
        for (int e = 0; e < 4; ++e) {
          float wa = (float)wv[e], wb2 = (float)wv[e + 4];
          A0 = fmaf(xa0[e], wa, A0); A1 = fmaf(xa1[e], wb2, A1);
          B0 = fmaf(xb0[e], wa, B0); B1 = fmaf(xb1[e], wb2, B1);
        }
      }
      #pragma unroll
      for (int kk = 0; kk < 64; kk += 8) {
        bf16x8 wv = *(const bf16x8*)&wg[128 + kk];
        f32x4 ha0 = *(const f32x4*)&h2[0][kk];
        f32x4 ha1 = *(const f32x4*)&h2[0][kk + 4];
        f32x4 hb0 = *(const f32x4*)&h2[1][kk];
        f32x4 hb1 = *(const f32x4*)&h2[1][kk + 4];
        #pragma unroll
        for (int e = 0; e < 4; ++e) {
          float wa = (float)wv[e], wb2 = (float)wv[e + 4];
          A0 = fmaf(ha0[e], wa, A0); A1 = fmaf(ha1[e], wb2, A1);
          B0 = fmaf(hb0[e], wa, B0); B1 = fmaf(hb1[e], wb2, B1);
        }
      }
      gl2[0][g] = biasg + A0 + A1;
      gl2[1][g] = biasg + B0 + B1;
    }
    __syncthreads();
    if (t < 128) {   // LSTM for both peds
      int pe = t >> 6, u = t & 63;
      float ig = gl2[pe][u], fg = gl2[pe][64 + u];
      float gg = gl2[pe][128 + u], og = gl2[pe][192 + u];
      float is = 1.f / (1.f + expf(-ig));
      float fs = 1.f / (1.f + expf(-fg));
      float os = 1.f / (1.f + expf(-og));
      float cn = fs * cs2[pe][u] + is * tanhf(gg);
      cs2[pe][u] = cn;
      h2[pe][u] = os * tanhf(cn);
    }
    __syncthreads();
    {   // Q (atomic->LLC) and P (LDS) for both peds
      int pe = t >> 7, which = (t >> 6) & 1, m = t & 63;
      int gp = b * 2 + pe;
      const __bf16* wr = w1T + which * 4096 + m * 64;
      float s0 = 0.f, s1 = 0.f;
      #pragma unroll
      for (int k = 0; k < 64; k += 8) {
        bf16x8 wv = *(const bf16x8*)&wr[k];
        f32x4 hv0 = *(const f32x4*)&h2[pe][k];
        f32x4 hv1 = *(const f32x4*)&h2[pe][k + 4];
        s0 = fmaf(hv0[0], (float)wv[0], s0); s1 = fmaf(hv0[1], (float)wv[1], s1);
        s0 = fmaf(hv0[2], (float)wv[2], s0); s1 = fmaf(hv0[3], (float)wv[3], s1);
        s0 = fmaf(hv1[0], (float)wv[4], s0); s1 = fmaf(hv1[1], (float)wv[5], s1);
        s0 = fmaf(hv1[2], (float)wv[6], s0); s1 = fmaf(hv1[3], (float)wv[7], s1);
      }
      float sv = s0 + s1;
      float px = pxy2[pe][0], py = pxy2[pe][1];
      if (which == 0) {
        float qv = sv + basev[m] - px * wcl[m] - py * wcl[64 + m];
        float qlo = __shfl(qv, (lane << 1));
        float qhi = __shfl(qv, (lane << 1) + 1);
        if (lane < 32) {
          BU ulo, uhi; ulo.h = (__bf16)qlo; uhi.h = (__bf16)qhi;
          unsigned int u32 = ((unsigned int)uhi.u << 16) | ulo.u;
          unsigned int* qdst =
              (unsigned int*)((__bf16*)(ws + OFF_QB) + (st & 1) * 32768);
          AT_ST32(qdst + gp * 32 + lane, u32);
        }
      } else {
        P2[pe][m] = sv + px * wcl[m] + py * wcl[64 + m];
      }
    }

    // ================= grid barrier (no fences) =================
    __syncthreads();
    if (t == 0) {
      __hip_atomic_fetch_add(&bar[st], 1, __ATOMIC_RELAXED, __HIP_MEMORY_SCOPE_AGENT);
      while (__hip_atomic_load(&bar[st], __ATOMIC_RELAXED, __HIP_MEMORY_SCOPE_AGENT) < NB)
        __builtin_amdgcn_s_sleep(2);
    }
    __syncthreads();

    // ================= pool phase: waves split the j-range =================
    const unsigned long long* qsrc =
        (const unsigned long long*)((__bf16*)(ws + OFF_QB) + (st & 1) * 32768);
    int gp0 = b * 2, gp1 = b * 2 + 1;
    const int* nei0 = nei + ((size_t)st * NP + gp0) * NP;
    const int* nei1 = nei + ((size_t)st * NP + gp1) * NP;
    float vmA0 = -1e30f, vmA1 = -1e30f, vmA2 = -1e30f, vmA3 = -1e30f;
    float vmB0 = -1e30f, vmB1 = -1e30f, vmB2 = -1e30f, vmB3 = -1e30f;
    f32x4 pa0 = *(const f32x4*)&P2[0][quad * 8];
    f32x4 pa1 = *(const f32x4*)&P2[0][quad * 8 + 4];
    f32x4 pb0 = *(const f32x4*)&P2[0][32 + quad * 8];
    f32x4 pb1 = *(const f32x4*)&P2[0][32 + quad * 8 + 4];
    f32x4 pc0 = *(const f32x4*)&P2[1][quad * 8];
    f32x4 pc1 = *(const f32x4*)&P2[1][quad * 8 + 4];
    f32x4 pd0 = *(const f32x4*)&P2[1][32 + quad * 8];
    f32x4 pd1 = *(const f32x4*)&P2[1][32 + quad * 8 + 4];

    unsigned long long v0, v1, v2, v3;
    v0 = AT_LD64(qsrc + 0 * 256 + t); v1 = AT_LD64(qsrc + 1 * 256 + t);
    v2 = AT_LD64(qsrc + 2 * 256 + t); v3 = AT_LD64(qsrc + 3 * 256 + t);
    {
      int f0 = t, f1 = 256 + t, f2 = 512 + t, f3 = 768 + t;
      *(unsigned long long*)&Qc[0][(f0 >> 4) * 72 + (f0 & 15) * 4] = v0;
      *(unsigned long long*)&Qc[0][(f1 >> 4) * 72 + (f1 & 15) * 4] = v1;
      *(unsigned long long*)&Qc[0][(f2 >> 4) * 72 + (f2 & 15) * 4] = v2;
      *(unsigned long long*)&Qc[0][(f3 >> 4) * 72 + (f3 & 15) * 4] = v3;
    }
    __syncthreads();

    for (int c = 0; c < 8; ++c) {
      int buf = c & 1;
      if (c < 7) {
        v0 = AT_LD64(qsrc + (c + 1) * 1024 + 0 * 256 + t);
        v1 = AT_LD64(qsrc + (c + 1) * 1024 + 1 * 256 + t);
        v2 = AT_LD64(qsrc + (c + 1) * 1024 + 2 * 256 + t);
        v3 = AT_LD64(qsrc + (c + 1) * 1024 + 3 * 256 + t);
      }
      int mv0 = nei0[c * 64 + lane];
      int mv1 = nei1[c * 64 + lane];
      int jrow = w * 16 + col;            // this wave's 16-j tile in the chunk
      bf16x8 q0 = *(const bf16x8*)&Qc[buf][jrow * 72 + quad * 8];
      bf16x8 q1 = *(const bf16x8*)&Qc[buf][jrow * 72 + 32 + quad * 8];
      int mrow = w * 16 + quad * 4;
      bool n00 = __shfl(mv0, mrow) > 0,     n01 = __shfl(mv0, mrow + 1) > 0;
      bool n02 = __shfl(mv0, mrow + 2) > 0, n03 = __shfl(mv0, mrow + 3) > 0;
      bool n10 = __shfl(mv1, mrow) > 0,     n11 = __shfl(mv1, mrow + 1) > 0;
      bool n12 = __shfl(mv1, mrow + 2) > 0, n13 = __shfl(mv1, mrow + 3) > 0;
      // ped 0
      {
        bf16x8 a0, a1;
        #pragma unroll
        for (int e = 0; e < 4; ++e) {
          a0[e]     = (__bf16)fmaxf((float)q0[e]     + pa0[e], 0.f);
          a0[e + 4] = (__bf16)fmaxf((float)q0[e + 4] + pa1[e], 0.f);
          a1[e]     = (__bf16)fmaxf((float)q1[e]     + pb0[e], 0.f);
          a1[e + 4] = (__bf16)fmaxf((float)q1[e + 4] + pb1[e], 0.f);
        }
        f32x4 acc;
        acc = (f32x4){0.f, 0.f, 0.f, 0.f};
        acc = __builtin_amdgcn_mfma_f32_16x16x32_bf16(a0, bf00, acc, 0, 0, 0);
        acc = __builtin_amdgcn_mfma_f32_16x16x32_bf16(a1, bf01, acc, 0, 0, 0);
        vmA0 = fmaxf(vmA0, n00 ? acc[0] : -1e30f);
        vmA0 = fmaxf(vmA0, n01 ? acc[1] : -1e30f);
        vmA0 = fmaxf(vmA0, n02 ? acc[2] : -1e30f);
        vmA0 = fmaxf(vmA0, n03 ? acc[3] : -1e30f);
        acc = (f32x4){0.f, 0.f, 0.f, 0.f};
        acc = __builtin_amdgcn_mfma_f32_16x16x32_bf16(a0, bf10, acc, 0, 0, 0);
        acc = __builtin_amdgcn_mfma_f32_16x16x32_bf16(a1, bf11, acc, 0, 0, 0);
        vmA1 = fmaxf(vmA1, n00 ? acc[0] : -1e30f);
        vmA1 = fmaxf(vmA1, n01 ? acc[1] : -1e30f);
        vmA1 = fmaxf(vmA1, n02 ? acc[2] : -1e30f);
        vmA1 = fmaxf(vmA1, n03 ? acc[3] : -1e30f);
        acc = (f32x4){0.f, 0.f, 0.f, 0.f};
        acc = __builtin_amdgcn_mfma_f32_16x16x32_bf16(a0, bf20, acc, 0, 0, 0);
        acc = __builtin_amdgcn_mfma_f32_16x16x32_bf16(a1, bf21, acc, 0, 0, 0);
        vmA2 = fmaxf(vmA2, n00 ? acc[0] : -1e30f);
        vmA2 = fmaxf(vmA2, n01 ? acc[1] : -1e30f);
        vmA2 = fmaxf(vmA2, n02 ? acc[2] : -1e30f);
        vmA2 = fmaxf(vmA2, n03 ? acc[3] : -1e30f);
        acc = (f32x4){0.f, 0.f, 0.f, 0.f};
        acc = __builtin_amdgcn_mfma_f32_16x16x32_bf16(a0, bf30, acc, 0, 0, 0);
        acc = __builtin_amdgcn_mfma_f32_16x16x32_bf16(a1, bf31, acc, 0, 0, 0);
        vmA3 = fmaxf(vmA3, n00 ? acc[0] : -1e30f);
        vmA3 = fmaxf(vmA3, n01 ? acc[1] : -1e30f);
        vmA3 = fmaxf(vmA3, n02 ? acc[2] : -1e30f);
        vmA3 = fmaxf(vmA3, n03 ? acc[3] : -1e30f);
      }
      // ped 1
      {
        bf16x8 a0, a1;
        #pragma unroll
        for (int e = 0; e < 4; ++e) {
          a0[e]     = (__bf16)fmaxf((float)q0[e]     + pc0[e], 0.f);
          a0[e + 4] = (__bf16)fmaxf((float)q0[e + 4] + pc1[e], 0.f);
          a1[e]     = (__bf16)fmaxf((float)q1[e]     + pd0[e], 0.f);
          a1[e + 4] = (__bf16)fmaxf((float)q1[e + 4] + pd1[e], 0.f);
        }
        f32x4 acc;
        acc = (f32x4){0.f, 0.f, 0.f, 0.f};
        acc = __builtin_amdgcn_mfma_f32_16x16x32_bf16(a0, bf00, acc, 0, 0, 0);
        acc = __builtin_amdgcn_mfma_f32_16x16x32_bf16(a1, bf01, acc, 0, 0, 0);
        vmB0 = fmaxf(vmB0, n10 ? acc[0] : -1e30f);
        vmB0 = fmaxf(vmB0, n11 ? acc[1] : -1e30f);
        vmB0 = fmaxf(vmB0, n12 ? acc[2] : -1e30f);
        vmB0 = fmaxf(vmB0, n13 ? acc[3] : -1e30f);
        acc = (f32x4){0.f, 0.f, 0.f, 0.f};
        acc = __builtin_amdgcn_mfma_f32_16x16x32_bf16(a0, bf10, acc, 0, 0, 0);
        acc = __builtin_amdgcn_mfma_f32_16x16x32_bf16(a1, bf11, acc, 0, 0, 0);
        vmB1 = fmaxf(vmB1, n10 ? acc[0] : -1e30f);
        vmB1 = fmaxf(vmB1, n11 ? acc[1] : -1e30f);
        vmB1 = fmaxf(vmB1, n12 ? acc[2] : -1e30f);
        vmB1 = fmaxf(vmB1, n13 ? acc[3] : -1e30f);
        acc = (f32x4){0.f, 0.f, 0.f, 0.f};
        acc = __builtin_amdgcn_mfma_f32_16x16x32_bf16(a0, bf20, acc, 0, 0, 0);
        acc = __builtin_amdgcn_mfma_f32_16x16x32_bf16(a1, bf21, acc, 0, 0, 0);
        vmB2 = fmaxf(vmB2, n10 ? acc[0] : -1e30f);
        vmB2 = fmaxf(vmB2, n11 ? acc[1] : -1e30f);
        vmB2 = fmaxf(vmB2, n12 ? acc[2] : -1e30f);
        vmB2 = fmaxf(vmB2, n13 ? acc[3] : -1e30f);
        acc = (f32x4){0.f, 0.f, 0.f, 0.f};
        acc = __builtin_amdgcn_mfma_f32_16x16x32_bf16(a0, bf30, acc, 0, 0, 0);
        acc = __builtin_amdgcn_mfma_f32_16x16x32_bf16(a1, bf31, acc, 0, 0, 0);
        vmB3 = fmaxf(vmB3, n10 ? acc[0] : -1e30f);
        vmB3 = fmaxf(vmB3, n11 ? acc[1] : -1e30f);
        vmB3 = fmaxf(vmB3, n12 ? acc[2] : -1e30f);
        vmB3 = fmaxf(vmB3, n13 ? acc[3] : -1e30f);
      }
      if (c < 7) {
        int nb2 = buf ^ 1;
        int f0 = t, f1 = 256 + t, f2 = 512 + t, f3 = 768 + t;
        *(unsigned long long*)&Qc[nb2][(f0 >> 4) * 72 + (f0 & 15) * 4] = v0;
        *(unsigned long long*)&Qc[nb2][(f1 >> 4) * 72 + (f1 & 15) * 4] = v1;
        *(unsigned long long*)&Qc[nb2][(f2 >> 4) * 72 + (f2 & 15) * 4] = v2;
        *(unsigned long long*)&Qc[nb2][(f3 >> 4) * 72 + (f3 & 15) * 4] = v3;
      }
      __syncthreads();
    }

    // cross-quad reduce within wave, then cross-wave via LDS
    vmA0 = fmaxf(vmA0, __shfl_xor(vmA0, 16)); vmA0 = fmaxf(vmA0, __shfl_xor(vmA0, 32));
    vmA1 = fmaxf(vmA1, __shfl_xor(vmA1, 16)); vmA1 = fmaxf(vmA1, __shfl_xor(vmA1, 32));
    vmA2 = fmaxf(vmA2, __shfl_xor(vmA2, 16)); vmA2 = fmaxf(vmA2, __shfl_xor(vmA2, 32));
    vmA3 = fmaxf(vmA3, __shfl_xor(vmA3, 16)); vmA3 = fmaxf(vmA3, __shfl_xor(vmA3, 32));
    vmB0 = fmaxf(vmB0, __shfl_xor(vmB0, 16)); vmB0 = fmaxf(vmB0, __shfl_xor(vmB0, 32));
    vmB1 = fmaxf(vmB1, __shfl_xor(vmB1, 16)); vmB1 = fmaxf(vmB1, __shfl_xor(vmB1, 32));
    vmB2 = fmaxf(vmB2, __shfl_xor(vmB2, 16)); vmB2 = fmaxf(vmB2, __shfl_xor(vmB2, 32));
    vmB3 = fmaxf(vmB3, __shfl_xor(vmB3, 16)); vmB3 = fmaxf(vmB3, __shfl_xor(vmB3, 32));
    if (lane < 16) {
      red[w][0][0 * 16 + lane] = vmA0;
      red[w][0][1 * 16 + lane] = vmA1;
      red[w][0][2 * 16 + lane] = vmA2;
      red[w][0][3 * 16 + lane] = vmA3;
      red[w][1][0 * 16 + lane] = vmB0;
      red[w][1][1 * 16 + lane] = vmB1;
      red[w][1][2 * 16 + lane] = vmB2;
      red[w][1][3 * 16 + lane] = vmB3;
    }
    __syncthreads();
    if (t < 128) {
      int pe = t >> 6, u = t & 63;
      float m4 = fmaxf(fmaxf(red[0][pe][u], red[1][pe][u]),
                       fmaxf(red[2][pe][u], red[3][pe][u]));
      ctx2[pe][u] = fmaxf(m4 + b2[u], 0.f);
    }
    __syncthreads();
    if (w < 2) {   // epilogue: wave w handles ped w
      int pe = w, gp = b * 2 + pe, l = lane;
      float cval = ctx2[pe][l];
      float sc0 = cval * Wl2p[(32 + l) * 2 + 0];
      float sc1 = cval * Wl2p[(32 + l) * 2 + 1];
      float e0s = 0.f, e1s = 0.f, f0s = 0.f, f1s = 0.f;
      if (l < 32) {
        float hm = h2[pe][l];
        e0s = hm * Wl2p[l * 2 + 0]; e1s = hm * Wl2p[l * 2 + 1];
        float hv = h2[pe][32 + l];
        f0s = hv * Wl2p[l * 2 + 0]; f1s = hv * Wl2p[l * 2 + 1];
      }
      for (int off = 32; off >= 1; off >>= 1) {
        sc0 += __shfl_down(sc0, off);
        sc1 += __shfl_down(sc1, off);
        e0s += __shfl_down(e0s, off);
        e1s += __shfl_down(e1s, off);
        f0s += __shfl_down(f0s, off);
        f1s += __shfl_down(f1s, off);
      }
      if (l == 0) {
        float mu0 = e0s + sc0 + bl2p[0], mu1 = e1s + sc1 + bl2p[1];
        float lv0 = f0s + sc0 + bl2p[0], lv1 = f1s + sc1 + bl2p[1];
        float ee0 = epsin[st * 1024 + gp * 2 + 0];
        float ee1 = epsin[st * 1024 + gp * 2 + 1];
        float p0 = mu0 + ee0 * expf(0.5f * lv0);
        float p1 = mu1 + ee1 * expf(0.5f * lv1);
        out[st * 1024 + gp * 2 + 0] = p0;
        out[st * 1024 + gp * 2 + 1] = p1;
        out[12288 + st * 1024 + gp * 2 + 0] = mu0;
        out[12288 + st * 1024 + gp * 2 + 1] = mu1;
        out[24576 + st * 1024 + gp * 2 + 0] = lv0;
        out[24576 + st * 1024 + gp * 2 + 1] = lv1;
        prev2[pe][0] = p0; prev2[pe][1] = p1;
        pxy2[pe][0] += p0; pxy2[pe][1] += p1;
      }
    }
    __syncthreads();
  }
}

extern "C" void kernel_launch(void* const* d_in, const int* in_sizes, int n_in,
                              void* d_out, int out_size, void* d_ws, size_t ws_size,
                              hipStream_t stream) {
  const float* lastpos = (const float*)d_in[0];
  const float* cc      = (const float*)d_in[1];
  const float* zz      = (const float*)d_in[2];
  const float* obs     = (const float*)d_in[3];
  const int*   nei     = (const int*)d_in[4];
  const float* h0      = (const float*)d_in[6];
  const float* c0      = (const float*)d_in[7];
  const float* eps     = (const float*)d_in[8];
  const float* W_in    = (const float*)d_in[9];
  const float* b_in    = (const float*)d_in[10];
  const float* W_ih    = (const float*)d_in[11];
  const float* W_hh    = (const float*)d_in[12];
  const float* b_ih    = (const float*)d_in[13];
  const float* b_hh    = (const float*)d_in[14];
  const float* W_l2p   = (const float*)d_in[15];
  const float* b_l2p   = (const float*)d_in[16];
  const float* W_sp    = (const float*)d_in[17];
  const float* b_sp    = (const float*)d_in[18];
  const float* W1      = (const float*)d_in[19];
  const float* b1      = (const float*)d_in[20];
  const float* W2      = (const float*)d_in[21];
  const float* b2      = (const float*)d_in[22];
  float* out = (float*)d_out;
  float* ws  = (float*)d_ws;

  hipLaunchKernelGGL(init_k, dim3(640), dim3(256), 0, stream,
                     cc, zz, W_in, W_ih, W_hh, W_sp, b_sp, W1, b1, W2, ws);
  hipLaunchKernelGGL(persist_k, dim3(NB), dim3(256), 0, stream,
                     lastpos, nei, h0, c0, obs, eps,
                     b_in, b_ih, b_hh, W_l2p, b_l2p, b2, out, ws);
}

// Round 16
// 337.038 us; speedup vs baseline: 2.1406x; 1.0949x over previous
//
#include <hip/hip_runtime.h>
#include <math.h>

#define NP 512
#define TT 12
#define NB 512   // persistent blocks; 1 ped each; launch_bounds(256,2) => 2/CU resident

typedef float f32x4 __attribute__((ext_vector_type(4)));
typedef __bf16 bf16x8 __attribute__((ext_vector_type(8)));

// ws float offsets (float units)
#define OFF_QB     0        // bf16 [12][512][64]  one buffer per step (196608 floats)
#define OFF_XCZ    196608   // f32 [512][128]
#define OFF_WGT    262144   // bf16 [256 g][192 k]
#define OFF_WCTXT  286720   // bf16 [128 k][64 d]
#define OFF_W1T    290816   // bf16 [2][64 m][64 k]
#define OFF_WIN01  294912   // f32 [2][128]
#define OFF_WC     295168   // f32 [2][64]
#define OFF_BASE   295296   // f32 [64]
#define OFF_W2F    295360   // bf16 [64 lane][64]
#define OFF_BAR    297408   // int [128]: [st*8+leaf] leaves, [96+st] roots
// total 297440 floats ~= 1.19 MB

#define AT_ADD(p)    __hip_atomic_fetch_add((p), 1, __ATOMIC_RELAXED, __HIP_MEMORY_SCOPE_AGENT)
#define AT_LDI(p)    __hip_atomic_load((p), __ATOMIC_RELAXED, __HIP_MEMORY_SCOPE_AGENT)
#define AT_ST32(p,v) __hip_atomic_store((p), (v), __ATOMIC_RELAXED, __HIP_MEMORY_SCOPE_AGENT)

union BU { __bf16 h; unsigned short u; };

__global__ __launch_bounds__(256) void init_k(
    const float* __restrict__ cc, const float* __restrict__ zz,
    const float* __restrict__ W_in, const float* __restrict__ W_ih,
    const float* __restrict__ W_hh, const float* __restrict__ W_sp,
    const float* __restrict__ b_sp, const float* __restrict__ W1,
    const float* __restrict__ b1, const float* __restrict__ W2,
    float* __restrict__ ws) {
  if (blockIdx.x < 128) {
    int id = blockIdx.x * 256 + threadIdx.x;   // 0..32767
    __bf16* wgt = (__bf16*)(ws + OFF_WGT);
    for (int e = id; e < 49152; e += 32768) {
      int g = e / 192, k = e - g * 192;
      wgt[e] = (__bf16)((k < 128) ? W_ih[g * 128 + k] : W_hh[g * 64 + (k - 128)]);
    }
    if (id < 8192) {   // WCTXT[k][d] = W_in[98+d][k]
      int k = id >> 6, d = id & 63;
      ((__bf16*)(ws + OFF_WCTXT))[id] = (__bf16)W_in[(98 + d) * 128 + k];
    }
    if (id < 8192) {   // W1T[which][m][k] = W1[32+which*64+k][m]
      int which = id >> 12, m = (id >> 6) & 63, k = id & 63;
      ((__bf16*)(ws + OFF_W1T))[id] = (__bf16)W1[(32 + which * 64 + k) * 64 + m];
    }
    if (id < 256) ws[OFF_WIN01 + id] = W_in[(id >> 7) * 128 + (id & 127)];
    if (id < 128) {
      int d = id >> 6, m = id & 63;
      float s = 0.f;
      for (int e = 0; e < 32; ++e) s = fmaf(W_sp[d * 32 + e], W1[e * 64 + m], s);
      ws[OFF_WC + id] = s;
    }
    if (id < 64) {
      float s = b1[id];
      for (int e = 0; e < 32; ++e) s = fmaf(b_sp[e], W1[e * 64 + id], s);
      ws[OFF_BASE + id] = s;
    }
    if (id < 4096) {   // W2 fragment table
      int e = id & 7, f = (id >> 3) & 7, cq = id >> 6;
      int col = cq >> 2, quad = cq & 3, mt = f >> 1, kh = f & 1;
      ((__bf16*)(ws + OFF_W2F))[id] =
          (__bf16)W2[(kh * 32 + quad * 8 + e) * 64 + (mt * 16 + col)];
    }
    if (id < 128) ((int*)(ws + OFF_BAR))[id] = 0;
  } else {
    int b = blockIdx.x - 128;
    int k = threadIdx.x;
    if (k < 128) {
      float s = 0.f;
      for (int d = 0; d < 64; ++d) s = fmaf(cc[b * 64 + d], W_in[(2 + d) * 128 + k], s);
      for (int d = 0; d < 32; ++d) s = fmaf(zz[b * 32 + d], W_in[(66 + d) * 128 + k], s);
      ws[OFF_XCZ + b * 128 + k] = s;
    }
  }
}

// Persistent: 512 blocks x 256 threads (2 blocks/CU), each owns 1 pedestrian.
// Q uses 12 per-step buffers: atomic stores (LLC) pre-barrier, NORMAL cached
// loads post-barrier (each address written once then read once -> no stale-L2
// hazard; L2 shares the lines across all blocks of an XCD). Barrier: 2-level
// (8 leaves x 64 + root), relaxed atomics, no fences.
__global__ __launch_bounds__(256, 2) void persist_k(
    const float* __restrict__ lastpos, const int* __restrict__ nei,
    const float* __restrict__ h0, const float* __restrict__ c0,
    const float* __restrict__ obs, const float* __restrict__ epsin,
    const float* __restrict__ b_in,
    const float* __restrict__ b_ih, const float* __restrict__ b_hh,
    const float* __restrict__ Wl2p, const float* __restrict__ bl2p,
    const float* __restrict__ b2,
    float* __restrict__ out, float* __restrict__ ws) {
  __shared__ __align__(16) float Pl[64], hl[64], csl[64], ctxl[64];
  __shared__ float prevl[2], pxyl[2];
  __shared__ __align__(16) float xv[128];
  __shared__ float gl[256];
  __shared__ float basev[64], wcl[128];
  __shared__ float red[4][64];

  int t = threadIdx.x;
  int b = blockIdx.x;          // = pedestrian id
  int lane = t & 63, w = t >> 6;
  int quad = lane >> 4, col = lane & 15;
  int* bar = (int*)(ws + OFF_BAR);
  const __bf16* wgt   = (const __bf16*)(ws + OFF_WGT);
  const __bf16* wctxT = (const __bf16*)(ws + OFF_WCTXT);
  const __bf16* w1T   = (const __bf16*)(ws + OFF_W1T);

  // ---- one-time init ----
  if (t < 64) {
    hl[t]  = h0[b * 64 + t];
    csl[t] = c0[b * 64 + t];
    ctxl[t] = 0.f;
    basev[t] = ws[OFF_BASE + t];
  } else if (t < 192) {
    wcl[t - 64] = ws[OFF_WC + (t - 64)];
  }
  if (t < 2) {
    prevl[t] = lastpos[b * 2 + t];
    pxyl[t]  = obs[7 * 1024 + b * 2 + t];
  }
  const __bf16* wf = (const __bf16*)(ws + OFF_W2F) + (col * 4 + quad) * 64;
  bf16x8 bf00 = *(const bf16x8*)&wf[0];
  bf16x8 bf01 = *(const bf16x8*)&wf[8];
  bf16x8 bf10 = *(const bf16x8*)&wf[16];
  bf16x8 bf11 = *(const bf16x8*)&wf[24];
  bf16x8 bf20 = *(const bf16x8*)&wf[32];
  bf16x8 bf21 = *(const bf16x8*)&wf[40];
  bf16x8 bf30 = *(const bf16x8*)&wf[48];
  bf16x8 bf31 = *(const bf16x8*)&wf[56];
  __syncthreads();

  for (int st = 0; st < TT; ++st) {
    // ================= row phase =================
    if (t < 128) {   // x[k] = relu(Xcz + prev@W_in[0:2] + ctx@W_in[98:162] + b_in)
      int k = t;
      float a0 = ws[OFF_XCZ + b * 128 + k] + b_in[k] +
                 prevl[0] * ws[OFF_WIN01 + k] +
                 prevl[1] * ws[OFF_WIN01 + 128 + k];
      const __bf16* wk = wctxT + k * 64;
      float s0 = 0.f, s1 = 0.f;
      #pragma unroll
      for (int d = 0; d < 64; d += 8) {
        bf16x8 wv = *(const bf16x8*)&wk[d];
        f32x4 c0v = *(const f32x4*)&ctxl[d];
        f32x4 c1v = *(const f32x4*)&ctxl[d + 4];
        s0 = fmaf(c0v[0], (float)wv[0], s0); s1 = fmaf(c0v[1], (float)wv[1], s1);
        s0 = fmaf(c0v[2], (float)wv[2], s0); s1 = fmaf(c0v[3], (float)wv[3], s1);
        s0 = fmaf(c1v[0], (float)wv[4], s0); s1 = fmaf(c1v[1], (float)wv[5], s1);
        s0 = fmaf(c1v[2], (float)wv[6], s0); s1 = fmaf(c1v[3], (float)wv[7], s1);
      }
      xv[k] = fmaxf(a0 + s0 + s1, 0.f);
    }
    __syncthreads();
    {   // gates
      int g = t;
      const __bf16* wg = wgt + g * 192;
      float A0 = 0.f, A1 = 0.f, A2 = 0.f, A3 = 0.f;
      #pragma unroll
      for (int kk = 0; kk < 128; kk += 8) {
        bf16x8 wv = *(const bf16x8*)&wg[kk];
        f32x4 xa0 = *(const f32x4*)&xv[kk];
        f32x4 xa1 = *(const f32x4*)&xv[kk + 4];
        A0 = fmaf(xa0[0], (float)wv[0], A0); A1 = fmaf(xa0[1], (float)wv[1], A1);
        A2 = fmaf(xa0[2], (float)wv[2], A2); A3 = fmaf(xa0[3], (float)wv[3], A3);
        A0 = fmaf(xa1[0], (float)wv[4], A0); A1 = fmaf(xa1[1], (float)wv[5], A1);
        A2 = fmaf(xa1[2], (float)wv[6], A2); A3 = fmaf(xa1[3], (float)wv[7], A3);
      }
      #pragma unroll
      for (int kk = 0; kk < 64; kk += 8) {
        bf16x8 wv = *(const bf16x8*)&wg[128 + kk];
        f32x4 ha0 = *(const f32x4*)&hl[kk];
        f32x4 ha1 = *(const f32x4*)&hl[kk + 4];
        A0 = fmaf(ha0[0], (float)wv[0], A0); A1 = fmaf(ha0[1], (float)wv[1], A1);
        A2 = fmaf(ha0[2], (float)wv[2], A2); A3 = fmaf(ha0[3], (float)wv[3], A3);
        A0 = fmaf(ha1[0], (float)wv[4], A0); A1 = fmaf(ha1[1], (float)wv[5], A1);
        A2 = fmaf(ha1[2], (float)wv[6], A2); A3 = fmaf(ha1[3], (float)wv[7], A3);
      }
      gl[g] = b_ih[g] + b_hh[g] + ((A0 + A1) + (A2 + A3));
    }
    __syncthreads();
    if (t < 64) {   // LSTM
      float ig = gl[t], fg = gl[64 + t], gg = gl[128 + t], og = gl[192 + t];
      float is = 1.f / (1.f + expf(-ig));
      float fs = 1.f / (1.f + expf(-fg));
      float os = 1.f / (1.f + expf(-og));
      float cn = fs * csl[t] + is * tanhf(gg);
      csl[t] = cn;
      hl[t] = os * tanhf(cn);
    }
    __syncthreads();
    if (t < 128) {   // Q (atomic->LLC per-step buffer), P (LDS)
      int which = t >> 6, m = t & 63;
      const __bf16* wr = w1T + which * 4096 + m * 64;
      float s0 = 0.f, s1 = 0.f;
      #pragma unroll
      for (int k = 0; k < 64; k += 8) {
        bf16x8 wv = *(const bf16x8*)&wr[k];
        f32x4 hv0 = *(const f32x4*)&hl[k];
        f32x4 hv1 = *(const f32x4*)&hl[k + 4];
        s0 = fmaf(hv0[0], (float)wv[0], s0); s1 = fmaf(hv0[1], (float)wv[1], s1);
        s0 = fmaf(hv0[2], (float)wv[2], s0); s1 = fmaf(hv0[3], (float)wv[3], s1);
        s0 = fmaf(hv1[0], (float)wv[4], s0); s1 = fmaf(hv1[1], (float)wv[5], s1);
        s0 = fmaf(hv1[2], (float)wv[6], s0); s1 = fmaf(hv1[3], (float)wv[7], s1);
      }
      float sv = s0 + s1;
      float px = pxyl[0], py = pxyl[1];
      if (which == 0) {
        float qv = sv + basev[m] - px * wcl[m] - py * wcl[64 + m];
        float qlo = __shfl(qv, (lane << 1));
        float qhi = __shfl(qv, (lane << 1) + 1);
        if (lane < 32) {
          BU ulo, uhi; ulo.h = (__bf16)qlo; uhi.h = (__bf16)qhi;
          unsigned int u32 = ((unsigned int)uhi.u << 16) | ulo.u;
          unsigned int* qdst =
              (unsigned int*)((__bf16*)(ws + OFF_QB) + st * 32768);
          AT_ST32(qdst + b * 32 + lane, u32);
        }
      } else {
        Pl[m] = sv + px * wcl[m] + py * wcl[64 + m];
      }
    }

    // ============ grid barrier: 8 leaves x 64 + root, no fences ============
    __syncthreads();    // drains wave-0's Q stores (vmcnt) before t0 proceeds
    if (t == 0) {
      int old = AT_ADD(&bar[st * 8 + (b & 7)]);
      if (old == 63) AT_ADD(&bar[96 + st]);
      while (AT_LDI(&bar[96 + st]) < 8) __builtin_amdgcn_s_sleep(2);
    }
    __syncthreads();

    // ================= pool phase (wave-autonomous, cached Q loads) ========
    const __bf16* qb = (const __bf16*)(ws + OFF_QB) + st * 32768;
    const int* neirow = nei + ((size_t)st * NP + b) * NP;
    float vm0 = -1e30f, vm1 = -1e30f, vm2 = -1e30f, vm3 = -1e30f;
    f32x4 pa0 = *(const f32x4*)&Pl[quad * 8];
    f32x4 pa1 = *(const f32x4*)&Pl[quad * 8 + 4];
    f32x4 pb0 = *(const f32x4*)&Pl[32 + quad * 8];
    f32x4 pb1 = *(const f32x4*)&Pl[32 + quad * 8 + 4];

    #pragma unroll 2
    for (int c = 0; c < 8; ++c) {
      int jg = c * 64 + w * 16 + col;          // this lane's j row
      bf16x8 q0 = *(const bf16x8*)&qb[jg * 64 + quad * 8];
      bf16x8 q1 = *(const bf16x8*)&qb[jg * 64 + 32 + quad * 8];
      int mv = neirow[c * 64 + lane];
      int mrow = w * 16 + quad * 4;
      bool n0 = __shfl(mv, mrow) > 0,     n1 = __shfl(mv, mrow + 1) > 0;
      bool n2 = __shfl(mv, mrow + 2) > 0, n3 = __shfl(mv, mrow + 3) > 0;
      bf16x8 a0, a1;
      #pragma unroll
      for (int e = 0; e < 4; ++e) {
        a0[e]     = (__bf16)fmaxf((float)q0[e]     + pa0[e], 0.f);
        a0[e + 4] = (__bf16)fmaxf((float)q0[e + 4] + pa1[e], 0.f);
        a1[e]     = (__bf16)fmaxf((float)q1[e]     + pb0[e], 0.f);
        a1[e + 4] = (__bf16)fmaxf((float)q1[e + 4] + pb1[e], 0.f);
      }
      f32x4 acc;
      acc = (f32x4){0.f, 0.f, 0.f, 0.f};
      acc = __builtin_amdgcn_mfma_f32_16x16x32_bf16(a0, bf00, acc, 0, 0, 0);
      acc = __builtin_amdgcn_mfma_f32_16x16x32_bf16(a1, bf01, acc, 0, 0, 0);
      vm0 = fmaxf(vm0, n0 ? acc[0] : -1e30f);
      vm0 = fmaxf(vm0, n1 ? acc[1] : -1e30f);
      vm0 = fmaxf(vm0, n2 ? acc[2] : -1e30f);
      vm0 = fmaxf(vm0, n3 ? acc[3] : -1e30f);
      acc = (f32x4){0.f, 0.f, 0.f, 0.f};
      acc = __builtin_amdgcn_mfma_f32_16x16x32_bf16(a0, bf10, acc, 0, 0, 0);
      acc = __builtin_amdgcn_mfma_f32_16x16x32_bf16(a1, bf11, acc, 0, 0, 0);
      vm1 = fmaxf(vm1, n0 ? acc[0] : -1e30f);
      vm1 = fmaxf(vm1, n1 ? acc[1] : -1e30f);
      vm1 = fmaxf(vm1, n2 ? acc[2] : -1e30f);
      vm1 = fmaxf(vm1, n3 ? acc[3] : -1e30f);
      acc = (f32x4){0.f, 0.f, 0.f, 0.f};
      acc = __builtin_amdgcn_mfma_f32_16x16x32_bf16(a0, bf20, acc, 0, 0, 0);
      acc = __builtin_amdgcn_mfma_f32_16x16x32_bf16(a1, bf21, acc, 0, 0, 0);
      vm2 = fmaxf(vm2, n0 ? acc[0] : -1e30f);
      vm2 = fmaxf(vm2, n1 ? acc[1] : -1e30f);
      vm2 = fmaxf(vm2, n2 ? acc[2] : -1e30f);
      vm2 = fmaxf(vm2, n3 ? acc[3] : -1e30f);
      acc = (f32x4){0.f, 0.f, 0.f, 0.f};
      acc = __builtin_amdgcn_mfma_f32_16x16x32_bf16(a0, bf30, acc, 0, 0, 0);
      acc = __builtin_amdgcn_mfma_f32_16x16x32_bf16(a1, bf31, acc, 0, 0, 0);
      vm3 = fmaxf(vm3, n0 ? acc[0] : -1e30f);
      vm3 = fmaxf(vm3, n1 ? acc[1] : -1e30f);
      vm3 = fmaxf(vm3, n2 ? acc[2] : -1e30f);
      vm3 = fmaxf(vm3, n3 ? acc[3] : -1e30f);
    }
    vm0 = fmaxf(vm0, __shfl_xor(vm0, 16)); vm0 = fmaxf(vm0, __shfl_xor(vm0, 32));
    vm1 = fmaxf(vm1, __shfl_xor(vm1, 16)); vm1 = fmaxf(vm1, __shfl_xor(vm1, 32));
    vm2 = fmaxf(vm2, __shfl_xor(vm2, 16)); vm2 = fmaxf(vm2, __shfl_xor(vm2, 32));
    vm3 = fmaxf(vm3, __shfl_xor(vm3, 16)); vm3 = fmaxf(vm3, __shfl_xor(vm3, 32));
    if (lane < 16) {
      red[w][0 * 16 + lane] = vm0;
      red[w][1 * 16 + lane] = vm1;
      red[w][2 * 16 + lane] = vm2;
      red[w][3 * 16 + lane] = vm3;
    }
    __syncthreads();
    if (t < 64) {
      float m4 = fmaxf(fmaxf(red[0][t], red[1][t]),
                       fmaxf(red[2][t], red[3][t]));
      ctxl[t] = fmaxf(m4 + b2[t], 0.f);
    }
    __syncthreads();
    if (w == 0) {   // epilogue
      int l = lane;
      float cval = ctxl[l];
      float sc0 = cval * Wl2p[(32 + l) * 2 + 0];
      float sc1 = cval * Wl2p[(32 + l) * 2 + 1];
      float e0s = 0.f, e1s = 0.f, f0s = 0.f, f1s = 0.f;
      if (l < 32) {
        float hm = hl[l];
        e0s = hm * Wl2p[l * 2 + 0]; e1s = hm * Wl2p[l * 2 + 1];
        float hv = hl[32 + l];
        f0s = hv * Wl2p[l * 2 + 0]; f1s = hv * Wl2p[l * 2 + 1];
      }
      for (int off = 32; off >= 1; off >>= 1) {
        sc0 += __shfl_down(sc0, off);
        sc1 += __shfl_down(sc1, off);
        e0s += __shfl_down(e0s, off);
        e1s += __shfl_down(e1s, off);
        f0s += __shfl_down(f0s, off);
        f1s += __shfl_down(f1s, off);
      }
      if (l == 0) {
        float mu0 = e0s + sc0 + bl2p[0], mu1 = e1s + sc1 + bl2p[1];
        float lv0 = f0s + sc0 + bl2p[0], lv1 = f1s + sc1 + bl2p[1];
        float ee0 = epsin[st * 1024 + b * 2 + 0];
        float ee1 = epsin[st * 1024 + b * 2 + 1];
        float p0 = mu0 + ee0 * expf(0.5f * lv0);
        float p1 = mu1 + ee1 * expf(0.5f * lv1);
        out[st * 1024 + b * 2 + 0] = p0;
        out[st * 1024 + b * 2 + 1] = p1;
        out[12288 + st * 1024 + b * 2 + 0] = mu0;
        out[12288 + st * 1024 + b * 2 + 1] = mu1;
        out[24576 + st * 1024 + b * 2 + 0] = lv0;
        out[24576 + st * 1024 + b * 2 + 1] = lv1;
        prevl[0] = p0; prevl[1] = p1;
        pxyl[0] += p0; pxyl[1] += p1;
      }
    }
    __syncthreads();
  }
}

extern "C" void kernel_launch(void* const* d_in, const int* in_sizes, int n_in,
                              void* d_out, int out_size, void* d_ws, size_t ws_size,
                              hipStream_t stream) {
  const float* lastpos = (const float*)d_in[0];
  const float* cc      = (const float*)d_in[1];
  const float* zz      = (const float*)d_in[2];
  const float* obs     = (const float*)d_in[3];
  const int*   nei     = (const int*)d_in[4];
  const float* h0      = (const float*)d_in[6];
  const float* c0      = (const float*)d_in[7];
  const float* eps     = (const float*)d_in[8];
  const float* W_in    = (const float*)d_in[9];
  const float* b_in    = (const float*)d_in[10];
  const float* W_ih    = (const float*)d_in[11];
  const float* W_hh    = (const float*)d_in[12];
  const float* b_ih    = (const float*)d_in[13];
  const float* b_hh    = (const float*)d_in[14];
  const float* W_l2p   = (const float*)d_in[15];
  const float* b_l2p   = (const float*)d_in[16];
  const float* W_sp    = (const float*)d_in[17];
  const float* b_sp    = (const float*)d_in[18];
  const float* W1      = (const float*)d_in[19];
  const float* b1      = (const float*)d_in[20];
  const float* W2      = (const float*)d_in[21];
  const float* b2      = (const float*)d_in[22];
  float* out = (float*)d_out;
  float* ws  = (float*)d_ws;

  hipLaunchKernelGGL(init_k, dim3(640), dim3(256), 0, stream,
                     cc, zz, W_in, W_ih, W_hh, W_sp, b_sp, W1, b1, W2, ws);
  hipLaunchKernelGGL(persist_k, dim3(NB), dim3(256), 0, stream,
                     lastpos, nei, h0, c0, obs, eps,
                     b_in, b_ih, b_hh, W_l2p, b_l2p, b2, out, ws);
}